// Round 8
// baseline (87.911 us; speedup 1.0000x reference)
//
#include <hip/hip_runtime.h>

// TrajLoss: pos = cumsum(pred.reshape(B,T,2), axis=1);
// loss = sum((pos_x - true[:, :T])^2 + (pos_y - true[:, T:])^2)
// B=8192, L=2048, T=1024. traj_du_true (d_in[1]) is unused by the reference.
//
// R1-R7 synthesis:
//  - K1 memory phase ~21-23 us is a delivery wall (~6.4 TB/s): invariant to
//    access pattern (R4==R5), HBM traffic (L3-resident replays identical),
//    occupancy (42% vs 70%).
//  - Same-address atomics cost ~8.5 ns each, serialized as an end tail
//    (R1: 2048 -> +17 us; R7: 512 -> +4 us). Avoid entirely.
//  - R4 (2-kernel, partials+K2) = 27.4; its remaining overhead is the K2
//    node + inter-node gap (~3-4 us).
// This version: ONE kernel node. R4's exact compute; per-block partial via
// agent-scope store; hierarchical last-block detection (32 padded bucket
// counters, 64 adds each -> tier-2 counter, 32 adds) and the single winner
// reduces the 2048 partials and writes out[0]. Counters are never zeroed:
// "last" is a residue test (ret&63==63), correct for ANY starting value
// (0xAA poison or leftovers) -> output never depends on prior state.

constexpr int L_DIM = 2048;
constexpr int T_DIM = 1024;          // L/2
constexpr int ROWS_PER_BLOCK = 4;    // 4 waves x 64 lanes

__global__ __launch_bounds__(256, 4) void traj_loss_kernel(
    const float* __restrict__ pred,
    const float* __restrict__ pos_true,
    float* __restrict__ partials,    // [gridDim.x]
    unsigned* __restrict__ c1,       // 32 counters, stride 16 u32 (64B lines)
    unsigned* __restrict__ c2,       // 1 counter
    float* __restrict__ out,
    int B)
{
    const int wid  = threadIdx.x >> 6;
    const int lane = threadIdx.x & 63;
    const int row  = blockIdx.x * ROWS_PER_BLOCK + wid;

    float acc = 0.0f;

    if (row < B) {
        const float4* p4 = reinterpret_cast<const float4*>(pred + (size_t)row * L_DIM);          // 512 float4
        const float4* tX = reinterpret_cast<const float4*>(pos_true + (size_t)row * L_DIM);      // 256 float4
        const float4* tY = reinterpret_cast<const float4*>(pos_true + (size_t)row * L_DIM + T_DIM);

        // ---- loads: lane owns 64 B contiguous per segment, 2 segments ----
        float4 v[2][4];     // pred: segment s, lane base s*256 + lane*4
        float4 tx[2][2];    // truth x: s*128 + lane*2
        float4 ty[2][2];
#pragma unroll
        for (int s = 0; s < 2; ++s)
#pragma unroll
            for (int q = 0; q < 4; ++q)
                v[s][q] = p4[s * 256 + lane * 4 + q];
#pragma unroll
        for (int s = 0; s < 2; ++s)
#pragma unroll
            for (int r = 0; r < 2; ++r)
                tx[s][r] = tX[s * 128 + lane * 2 + r];
#pragma unroll
        for (int s = 0; s < 2; ++s)
#pragma unroll
            for (int r = 0; r < 2; ++r)
                ty[s][r] = tY[s * 128 + lane * 2 + r];

        // ---- per-lane segment totals ----
        float sx[2], sy[2];
#pragma unroll
        for (int s = 0; s < 2; ++s) {
            sx[s] = (v[s][0].x + v[s][0].z) + (v[s][1].x + v[s][1].z)
                  + (v[s][2].x + v[s][2].z) + (v[s][3].x + v[s][3].z);
            sy[s] = (v[s][0].y + v[s][0].w) + (v[s][1].y + v[s][1].w)
                  + (v[s][2].y + v[s][2].w) + (v[s][3].y + v[s][3].w);
        }

        // ---- 2 segments x 2 axes wave inclusive scans (interleaved) ----
        float ix0 = sx[0], ix1 = sx[1], iy0 = sy[0], iy1 = sy[1];
#pragma unroll
        for (int d = 1; d < 64; d <<= 1) {
            float a = __shfl_up(ix0, d);
            float b = __shfl_up(ix1, d);
            float c = __shfl_up(iy0, d);
            float e = __shfl_up(iy1, d);
            if (lane >= d) { ix0 += a; ix1 += b; iy0 += c; iy1 += e; }
        }
        const float totx0 = __shfl(ix0, 63);   // segment-0 row total
        const float toty0 = __shfl(iy0, 63);

        // ---- error accumulation (all indices compile-time static) ----
#define SEG(s, bx, by)                                                  \
        { float rx = (bx), ry = (by), e;                                \
          rx += v[s][0].x; e = rx - tx[s][0].x; acc += e * e;           \
          ry += v[s][0].y; e = ry - ty[s][0].x; acc += e * e;           \
          rx += v[s][0].z; e = rx - tx[s][0].y; acc += e * e;           \
          ry += v[s][0].w; e = ry - ty[s][0].y; acc += e * e;           \
          rx += v[s][1].x; e = rx - tx[s][0].z; acc += e * e;           \
          ry += v[s][1].y; e = ry - ty[s][0].z; acc += e * e;           \
          rx += v[s][1].z; e = rx - tx[s][0].w; acc += e * e;           \
          ry += v[s][1].w; e = ry - ty[s][0].w; acc += e * e;           \
          rx += v[s][2].x; e = rx - tx[s][1].x; acc += e * e;           \
          ry += v[s][2].y; e = ry - ty[s][1].x; acc += e * e;           \
          rx += v[s][2].z; e = rx - tx[s][1].y; acc += e * e;           \
          ry += v[s][2].w; e = ry - ty[s][1].y; acc += e * e;           \
          rx += v[s][3].x; e = rx - tx[s][1].z; acc += e * e;           \
          ry += v[s][3].y; e = ry - ty[s][1].z; acc += e * e;           \
          rx += v[s][3].z; e = rx - tx[s][1].w; acc += e * e;           \
          ry += v[s][3].w; e = ry - ty[s][1].w; acc += e * e; }

        SEG(0, ix0 - sx[0],         iy0 - sy[0]);
        SEG(1, totx0 + ix1 - sx[1], toty0 + iy1 - sy[1]);
#undef SEG
    }

    // ---- wave reduce ----
#pragma unroll
    for (int d = 32; d >= 1; d >>= 1) acc += __shfl_xor(acc, d);

    __shared__ float warp_sums[ROWS_PER_BLOCK];
    __shared__ int is_last;
    if (lane == 0) warp_sums[wid] = acc;
    __syncthreads();

    if (threadIdx.x == 0) {
        float s = 0.0f;
#pragma unroll
        for (int w = 0; w < ROWS_PER_BLOCK; ++w) s += warp_sums[w];
        // agent-scope store: partial lands at the device-coherent point
        __hip_atomic_store(&partials[blockIdx.x], s,
                           __ATOMIC_RELAXED, __HIP_MEMORY_SCOPE_AGENT);
        // tier-1: 64 blocks per padded counter; release orders the store
        int last = 0;
        unsigned r1 = __hip_atomic_fetch_add(&c1[(blockIdx.x >> 6) * 16], 1u,
                                             __ATOMIC_ACQ_REL, __HIP_MEMORY_SCOPE_AGENT);
        if ((r1 & 63u) == 63u) {           // bucket-last (any start value)
            unsigned r2 = __hip_atomic_fetch_add(c2, 1u,
                                                 __ATOMIC_ACQ_REL, __HIP_MEMORY_SCOPE_AGENT);
            last = ((r2 & 31u) == 31u);    // global-last
        }
        is_last = last;
    }
    __syncthreads();
    if (!is_last) return;

    // ---- global-last block: reduce all partials, write result ----
    const int nblocks = gridDim.x;
    float s = 0.0f;
    for (int i = threadIdx.x; i < nblocks; i += 256)
        s += __hip_atomic_load(&partials[i], __ATOMIC_RELAXED, __HIP_MEMORY_SCOPE_AGENT);
#pragma unroll
    for (int d = 32; d >= 1; d >>= 1) s += __shfl_xor(s, d);

    if (lane == 0) warp_sums[wid] = s;
    __syncthreads();
    if (threadIdx.x == 0)
        out[0] = warp_sums[0] + warp_sums[1] + warp_sums[2] + warp_sums[3];
}

extern "C" void kernel_launch(void* const* d_in, const int* in_sizes, int n_in,
                              void* d_out, int out_size, void* d_ws, size_t ws_size,
                              hipStream_t stream) {
    const float* pred     = (const float*)d_in[0];  // traj_pred
    // d_in[1] = traj_du_true — unused by the reference
    const float* pos_true = (const float*)d_in[2];  // traj_pos_true
    float* out = (float*)d_out;

    const int B = in_sizes[0] / L_DIM;                            // 8192
    const int grid = (B + ROWS_PER_BLOCK - 1) / ROWS_PER_BLOCK;   // 2048

    // ws layout: [0,grid) partials | 32 padded u32 counters | 1 u32 counter
    float*    partials = (float*)d_ws;
    unsigned* c1       = (unsigned*)d_ws + grid;          // stride 16 (64 B)
    unsigned* c2       = (unsigned*)d_ws + grid + 32 * 16;

    traj_loss_kernel<<<grid, 256, 0, stream>>>(pred, pos_true, partials, c1, c2, out, B);
}

// Round 9
// 27.680 us; speedup vs baseline: 3.1760x; 3.1760x over previous
//
#include <hip/hip_runtime.h>

// TrajLoss: pos = cumsum(pred.reshape(B,T,2), axis=1);
// loss = sum((pos_x - true[:, :T])^2 + (pos_y - true[:, T:])^2)
// B=8192, L=2048, T=1024. traj_du_true (d_in[1]) is unused by the reference.
//
// FINAL (revert to R4, the measured optimum of 8 structural variants):
//  - K1 memory phase ~23 us is a delivery wall (~5.7 TB/s, 90% of the
//    6.3 TB/s achievable ceiling): invariant to access pattern (strided ==
//    coalesced), to HBM vs L3 residency, and to occupancy (25-70%).
//  - Same-address fp32 atomics drain at ~22 ns/op (2048 -> +24 us tail);
//    any contended-atomic ending loses to a second kernel node.
//  - Cross-XCD plain-store/flag handoff (last-block reduce) is broken AND
//    slow on gfx950: agent-scope ACQ_REL forces L2 wb/inv per op (R8).
// Structure: K1 = 2048 blocks x 4 waves, one row per wave, per-block
// partial -> d_ws via plain store; K2 = one 256-thread block reduces the
// 2048 partials into out[0]. Total = 21.3 us mandatory-bytes floor
// + ~2 us scan/request-path exposure + ~3.5 us second-node floor.

constexpr int L_DIM = 2048;
constexpr int T_DIM = 1024;          // L/2
constexpr int ROWS_PER_BLOCK = 4;    // 4 waves x 64 lanes

__global__ __launch_bounds__(256, 4) void traj_loss_kernel(
    const float* __restrict__ pred,
    const float* __restrict__ pos_true,
    float* __restrict__ partials,
    int B)
{
    const int wid  = threadIdx.x >> 6;
    const int lane = threadIdx.x & 63;
    const int row  = blockIdx.x * ROWS_PER_BLOCK + wid;

    float acc = 0.0f;

    if (row < B) {
        const float4* p4 = reinterpret_cast<const float4*>(pred + (size_t)row * L_DIM);          // 512 float4
        const float4* tX = reinterpret_cast<const float4*>(pos_true + (size_t)row * L_DIM);      // 256 float4
        const float4* tY = reinterpret_cast<const float4*>(pos_true + (size_t)row * L_DIM + T_DIM);

        // ---- loads: lane owns 64 B contiguous per segment, 2 segments ----
        float4 v[2][4];     // pred: segment s, lane base s*256 + lane*4
        float4 tx[2][2];    // truth x: s*128 + lane*2
        float4 ty[2][2];
#pragma unroll
        for (int s = 0; s < 2; ++s)
#pragma unroll
            for (int q = 0; q < 4; ++q)
                v[s][q] = p4[s * 256 + lane * 4 + q];
#pragma unroll
        for (int s = 0; s < 2; ++s)
#pragma unroll
            for (int r = 0; r < 2; ++r)
                tx[s][r] = tX[s * 128 + lane * 2 + r];
#pragma unroll
        for (int s = 0; s < 2; ++s)
#pragma unroll
            for (int r = 0; r < 2; ++r)
                ty[s][r] = tY[s * 128 + lane * 2 + r];

        // ---- per-lane segment totals ----
        float sx[2], sy[2];
#pragma unroll
        for (int s = 0; s < 2; ++s) {
            sx[s] = (v[s][0].x + v[s][0].z) + (v[s][1].x + v[s][1].z)
                  + (v[s][2].x + v[s][2].z) + (v[s][3].x + v[s][3].z);
            sy[s] = (v[s][0].y + v[s][0].w) + (v[s][1].y + v[s][1].w)
                  + (v[s][2].y + v[s][2].w) + (v[s][3].y + v[s][3].w);
        }

        // ---- 2 segments x 2 axes wave inclusive scans (interleaved) ----
        float ix0 = sx[0], ix1 = sx[1], iy0 = sy[0], iy1 = sy[1];
#pragma unroll
        for (int d = 1; d < 64; d <<= 1) {
            float a = __shfl_up(ix0, d);
            float b = __shfl_up(ix1, d);
            float c = __shfl_up(iy0, d);
            float e = __shfl_up(iy1, d);
            if (lane >= d) { ix0 += a; ix1 += b; iy0 += c; iy1 += e; }
        }
        const float totx0 = __shfl(ix0, 63);   // segment-0 row total
        const float toty0 = __shfl(iy0, 63);

        // ---- error accumulation (all indices compile-time static) ----
#define SEG(s, bx, by)                                                  \
        { float rx = (bx), ry = (by), e;                                \
          rx += v[s][0].x; e = rx - tx[s][0].x; acc += e * e;           \
          ry += v[s][0].y; e = ry - ty[s][0].x; acc += e * e;           \
          rx += v[s][0].z; e = rx - tx[s][0].y; acc += e * e;           \
          ry += v[s][0].w; e = ry - ty[s][0].y; acc += e * e;           \
          rx += v[s][1].x; e = rx - tx[s][0].z; acc += e * e;           \
          ry += v[s][1].y; e = ry - ty[s][0].z; acc += e * e;           \
          rx += v[s][1].z; e = rx - tx[s][0].w; acc += e * e;           \
          ry += v[s][1].w; e = ry - ty[s][0].w; acc += e * e;           \
          rx += v[s][2].x; e = rx - tx[s][1].x; acc += e * e;           \
          ry += v[s][2].y; e = ry - ty[s][1].x; acc += e * e;           \
          rx += v[s][2].z; e = rx - tx[s][1].y; acc += e * e;           \
          ry += v[s][2].w; e = ry - ty[s][1].y; acc += e * e;           \
          rx += v[s][3].x; e = rx - tx[s][1].z; acc += e * e;           \
          ry += v[s][3].y; e = ry - ty[s][1].z; acc += e * e;           \
          rx += v[s][3].z; e = rx - tx[s][1].w; acc += e * e;           \
          ry += v[s][3].w; e = ry - ty[s][1].w; acc += e * e; }

        SEG(0, ix0 - sx[0],         iy0 - sy[0]);
        SEG(1, totx0 + ix1 - sx[1], toty0 + iy1 - sy[1]);
#undef SEG
    }

    // ---- wave reduce ----
#pragma unroll
    for (int d = 32; d >= 1; d >>= 1) acc += __shfl_xor(acc, d);

    __shared__ float warp_sums[ROWS_PER_BLOCK];
    if (lane == 0) warp_sums[wid] = acc;
    __syncthreads();

    if (threadIdx.x == 0) {
        float s = 0.0f;
#pragma unroll
        for (int w = 0; w < ROWS_PER_BLOCK; ++w) s += warp_sums[w];
        partials[blockIdx.x] = s;   // plain store — no atomic contention
    }
}

__global__ __launch_bounds__(256) void reduce_kernel(
    const float* __restrict__ partials, float* __restrict__ out, int n)
{
    const int lane = threadIdx.x & 63;
    const int wid  = threadIdx.x >> 6;

    float s = 0.0f;
    for (int i = threadIdx.x; i < n; i += 256) s += partials[i];

#pragma unroll
    for (int d = 32; d >= 1; d >>= 1) s += __shfl_xor(s, d);

    __shared__ float ws[4];
    if (lane == 0) ws[wid] = s;
    __syncthreads();

    if (threadIdx.x == 0) out[0] = ws[0] + ws[1] + ws[2] + ws[3];
}

extern "C" void kernel_launch(void* const* d_in, const int* in_sizes, int n_in,
                              void* d_out, int out_size, void* d_ws, size_t ws_size,
                              hipStream_t stream) {
    const float* pred     = (const float*)d_in[0];  // traj_pred
    // d_in[1] = traj_du_true — unused by the reference
    const float* pos_true = (const float*)d_in[2];  // traj_pos_true
    float* out      = (float*)d_out;
    float* partials = (float*)d_ws;                 // grid floats, overwritten every call

    const int B = in_sizes[0] / L_DIM;
    const int grid = (B + ROWS_PER_BLOCK - 1) / ROWS_PER_BLOCK;   // 2048

    traj_loss_kernel<<<grid, 256, 0, stream>>>(pred, pos_true, partials, B);
    reduce_kernel<<<1, 256, 0, stream>>>(partials, out, grid);
}